// Round 1
// baseline (241.785 us; speedup 1.0000x reference)
//
#include <hip/hip_runtime.h>
#include <math.h>

#define NFIELDS 50
#define EMBD 64
#define ATTD 32
#define NPAIRS 1225      // 50*49/2
#define NTHREADS 256
#define ESTRIDE 52       // NFIELDS + 2 pad: per-lane reads hit consecutive banks

__launch_bounds__(NTHREADS, 4)
__global__ void afm_kernel(const int* __restrict__ features,
                           const float* __restrict__ emb_table,
                           const float* __restrict__ coeff_table,
                           const float* __restrict__ bias,
                           const float* __restrict__ att_w,
                           const float* __restrict__ att_b,
                           const float* __restrict__ pvec,
                           const float* __restrict__ wvec,
                           float* __restrict__ out)
{
    __shared__ float emb_t[EMBD][ESTRIDE];   // transposed: emb_t[d][field]
    __shared__ float attw_s[ATTD * EMBD];    // [a][d] row-major, broadcast reads
    __shared__ float w_s[EMBD];
    __shared__ float p_s[ATTD];
    __shared__ float attb_s[ATTD];
    __shared__ float coeff_s[NFIELDS];
    __shared__ int   feat_s[NFIELDS];
    __shared__ unsigned short iu_s[NPAIRS], ju_s[NPAIRS];
    __shared__ float red_max[4], red_sum[4], red_sumt[4];

    const int b = blockIdx.x;
    const int tid = threadIdx.x;

    // ---- phase 0a: features, coeff, small tables, pair-index tables ----
    if (tid < NFIELDS) {
        int f = features[b * NFIELDS + tid];
        feat_s[tid] = f;
        coeff_s[tid] = coeff_table[f];
    }
    for (int q = tid; q < ATTD * EMBD; q += NTHREADS) attw_s[q] = att_w[q];
    if (tid < EMBD) w_s[tid] = wvec[tid];
    if (tid >= 64 && tid < 64 + ATTD) p_s[tid - 64] = pvec[tid - 64];
    if (tid >= 96 && tid < 96 + ATTD) attb_s[tid - 96] = att_b[tid - 96];
    if (tid >= 128 && tid < 128 + NFIELDS - 1) {
        int i = tid - 128;                       // row 0..48
        int off = i * NFIELDS - (i * (i + 1)) / 2;
        int cnt = NFIELDS - 1 - i;
        for (int k = 0; k < cnt; ++k) {
            iu_s[off + k] = (unsigned short)i;
            ju_s[off + k] = (unsigned short)(i + 1 + k);
        }
    }
    __syncthreads();

    // ---- phase 0b: gather embeddings, store transposed in LDS ----
    for (int q = tid; q < NFIELDS * (EMBD / 4); q += NTHREADS) {
        int i = q >> 4;            // field
        int d0 = (q & 15) * 4;     // dim start
        const float4 v = *reinterpret_cast<const float4*>(
            &emb_table[(size_t)feat_s[i] * EMBD + d0]);
        emb_t[d0 + 0][i] = v.x; emb_t[d0 + 1][i] = v.y;
        emb_t[d0 + 2][i] = v.z; emb_t[d0 + 3][i] = v.w;
    }
    __syncthreads();

    // ---- phase 1: per-pair score + t = inter . w (pair-per-lane) ----
    float scv[5], tv[5];
    #pragma unroll
    for (int k = 0; k < 5; ++k) { scv[k] = -INFINITY; tv[k] = 0.f; }

    #pragma unroll
    for (int k = 0; k < 5; ++k) {
        int pp = tid + k * NTHREADS;
        if (pp < NPAIRS) {
            const int i = iu_s[pp];
            const int j = ju_s[pp];
            float h[ATTD];
            #pragma unroll
            for (int a = 0; a < ATTD; ++a) h[a] = 0.f;
            float t = 0.f;
            #pragma unroll 2
            for (int d4 = 0; d4 < EMBD; d4 += 4) {
                float x0 = emb_t[d4 + 0][i] * emb_t[d4 + 0][j];
                float x1 = emb_t[d4 + 1][i] * emb_t[d4 + 1][j];
                float x2 = emb_t[d4 + 2][i] * emb_t[d4 + 2][j];
                float x3 = emb_t[d4 + 3][i] * emb_t[d4 + 3][j];
                t = fmaf(x0, w_s[d4 + 0], t);
                t = fmaf(x1, w_s[d4 + 1], t);
                t = fmaf(x2, w_s[d4 + 2], t);
                t = fmaf(x3, w_s[d4 + 3], t);
                #pragma unroll
                for (int a = 0; a < ATTD; ++a) {
                    const float4 wa = *reinterpret_cast<const float4*>(&attw_s[a * EMBD + d4]);
                    h[a] = fmaf(x0, wa.x, fmaf(x1, wa.y, fmaf(x2, wa.z, fmaf(x3, wa.w, h[a]))));
                }
            }
            float sc = 0.f;
            #pragma unroll
            for (int a = 0; a < ATTD; ++a)
                sc += fmaxf(h[a] + attb_s[a], 0.f) * p_s[a];
            scv[k] = sc; tv[k] = t;
        }
    }

    // ---- phase 2: softmax (max, sum e, sum e*t) + output ----
    float lmax = -INFINITY;
    #pragma unroll
    for (int k = 0; k < 5; ++k) lmax = fmaxf(lmax, scv[k]);
    #pragma unroll
    for (int m = 1; m < 64; m <<= 1) lmax = fmaxf(lmax, __shfl_xor(lmax, m, 64));
    const int wid = tid >> 6;
    if ((tid & 63) == 0) red_max[wid] = lmax;
    __syncthreads();
    const float gmax = fmaxf(fmaxf(red_max[0], red_max[1]),
                             fmaxf(red_max[2], red_max[3]));

    float lsum = 0.f, lsumt = 0.f;
    #pragma unroll
    for (int k = 0; k < 5; ++k) {
        if (scv[k] != -INFINITY) {
            float e = __expf(scv[k] - gmax);
            lsum += e;
            lsumt += e * tv[k];
        }
    }
    #pragma unroll
    for (int m = 1; m < 64; m <<= 1) {
        lsum  += __shfl_xor(lsum, m, 64);
        lsumt += __shfl_xor(lsumt, m, 64);
    }
    if ((tid & 63) == 0) { red_sum[wid] = lsum; red_sumt[wid] = lsumt; }
    __syncthreads();

    if (tid == 0) {
        float S  = red_sum[0] + red_sum[1] + red_sum[2] + red_sum[3];
        float ST = red_sumt[0] + red_sumt[1] + red_sumt[2] + red_sumt[3];
        float csum = 0.f;
        for (int i = 0; i < NFIELDS; ++i) csum += coeff_s[i];
        out[b] = ST / S + csum + bias[0];
    }
}

extern "C" void kernel_launch(void* const* d_in, const int* in_sizes, int n_in,
                              void* d_out, int out_size, void* d_ws, size_t ws_size,
                              hipStream_t stream) {
    const int*   features    = (const int*)d_in[0];
    const float* emb_table   = (const float*)d_in[1];
    const float* coeff_table = (const float*)d_in[2];
    const float* bias        = (const float*)d_in[3];
    const float* att_w       = (const float*)d_in[4];
    const float* att_b       = (const float*)d_in[5];
    const float* pvec        = (const float*)d_in[6];
    const float* wvec        = (const float*)d_in[7];
    float* out = (float*)d_out;

    const int batch = in_sizes[0] / NFIELDS;   // 2048
    afm_kernel<<<batch, NTHREADS, 0, stream>>>(
        features, emb_table, coeff_table, bias, att_w, att_b, pvec, wvec, out);
}

// Round 2
// 45.186 us; speedup vs baseline: 5.3509x; 5.3509x over previous
//
#include <hip/hip_runtime.h>
#include <hip/hip_fp16.h>
#include <math.h>

#define NFIELDS 50
#define EMBD 64
#define ATTD 32
#define NPAIRS 1225
#define NPAD 1248          // 39 * 32
#define NTILES 39
#define NTHREADS 256
#define NWAVES 4
#define EHSTRIDE 68        // halves per row -> 136B rows: b64 reads are 2-way (free)
#define MAXT 10

typedef _Float16 f16x8 __attribute__((ext_vector_type(8)));
typedef _Float16 f16x2 __attribute__((ext_vector_type(2)));
typedef float f32x16 __attribute__((ext_vector_type(16)));

union U32F { unsigned int u; f16x2 h; };
union F16x8U { f16x8 v; f16x2 h2[4]; unsigned int u[4]; };

__device__ __forceinline__ float dot2acc(f16x2 a, f16x2 b, float c) {
#if __has_builtin(__builtin_amdgcn_fdot2)
    return __builtin_amdgcn_fdot2(a, b, c, false);
#else
    return c + (float)a[0] * (float)b[0] + (float)a[1] * (float)b[1];
#endif
}

__launch_bounds__(NTHREADS, 3)
__global__ void afm_kernel(const int* __restrict__ features,
                           const float* __restrict__ emb_table,
                           const float* __restrict__ coeff_table,
                           const float* __restrict__ bias,
                           const float* __restrict__ att_w,
                           const float* __restrict__ att_b,
                           const float* __restrict__ pvec,
                           const float* __restrict__ wvec,
                           float* __restrict__ out)
{
    __shared__ __align__(16) unsigned short emb_h[NFIELDS][EHSTRIDE]; // f16 bits
    __shared__ unsigned short iu_s[NPAD], ju_s[NPAD];
    __shared__ int   feat_s[NFIELDS];
    __shared__ float coeff_s[NFIELDS];
    __shared__ float red_max[NWAVES], red_sum[NWAVES], red_sumt[NWAVES];

    const int b   = blockIdx.x;
    const int tid = threadIdx.x;
    const int lane = tid & 63;
    const int wid  = tid >> 6;
    const int col  = lane & 31;   // MFMA output col = attention unit a; A row index
    const int h    = lane >> 5;   // k-group half

    // ---- phase 0a: features, coeff, pair-index tables ----
    if (tid < NFIELDS) {
        int f = features[b * NFIELDS + tid];
        feat_s[tid] = f;
        coeff_s[tid] = coeff_table[f];
    }
    if (tid >= 64 && tid < 64 + NFIELDS - 1) {
        int i = tid - 64;                         // row 0..48
        int off = i * NFIELDS - (i * (i + 1)) / 2;
        int cnt = NFIELDS - 1 - i;
        for (int k = 0; k < cnt; ++k) {
            iu_s[off + k] = (unsigned short)i;
            ju_s[off + k] = (unsigned short)(i + 1 + k);
        }
    }
    if (tid == 113) {
        for (int q = NPAIRS; q < NPAD; ++q) { iu_s[q] = 0; ju_s[q] = 1; }
    }

    // ---- per-lane register weights (global loads, no LDS) ----
    // B-frag: b[c][e] = W[col][c*16 + h*8 + e]   (fp32 -> f16)
    f16x8 bfrag[4];
    f16x2 w2[16];
    #pragma unroll
    for (int c = 0; c < 4; ++c) {
        F16x8U bf;
        const int d0 = c * 16 + h * 8;
        #pragma unroll
        for (int e = 0; e < 8; ++e)
            bf.v[e] = (_Float16)att_w[col * EMBD + d0 + e];
        bfrag[c] = bf.v;
        #pragma unroll
        for (int q = 0; q < 4; ++q) {
            f16x2 ww;
            ww[0] = (_Float16)wvec[d0 + 2 * q];
            ww[1] = (_Float16)wvec[d0 + 2 * q + 1];
            w2[c * 4 + q] = ww;
        }
    }
    const float attb_l = att_b[col];
    const float p_l    = pvec[col];

    __syncthreads();

    // ---- phase 0b: gather embeddings -> f16 in LDS ----
    for (int q = tid; q < NFIELDS * 16; q += NTHREADS) {
        int f  = q >> 4;
        int d0 = (q & 15) * 4;
        const float4 v = *reinterpret_cast<const float4*>(
            &emb_table[(size_t)feat_s[f] * EMBD + d0]);
        union { unsigned short s[4]; uint2 u; } pk;
        U32F t0, t1;
        t0.h[0] = (_Float16)v.x; t0.h[1] = (_Float16)v.y;
        t1.h[0] = (_Float16)v.z; t1.h[1] = (_Float16)v.w;
        pk.u.x = t0.u; pk.u.y = t1.u;
        *reinterpret_cast<uint2*>(&emb_h[f][d0]) = pk.u;
    }
    __syncthreads();

    // ---- main: per-wave 32-pair MFMA tiles ----
    float scv[MAXT], tv[MAXT];
    #pragma unroll
    for (int k = 0; k < MAXT; ++k) { scv[k] = -INFINITY; tv[k] = 0.f; }

    #pragma unroll
    for (int tt = 0; tt < MAXT; ++tt) {
        const int tile = wid + tt * NWAVES;
        if (tile < NTILES) {
            const int r = lane & 31;             // A-operand row (pair within tile)
            const int pidx = tile * 32 + r;
            const int fi = iu_s[pidx];
            const int fj = ju_s[pidx];
            const unsigned short* ei = &emb_h[fi][h * 8];
            const unsigned short* ej = &emb_h[fj][h * 8];

            f32x16 acc;
            #pragma unroll
            for (int k = 0; k < 16; ++k) acc[k] = 0.f;

            float t_half = 0.f;
            f16x8 afrag[4];
            #pragma unroll
            for (int c = 0; c < 4; ++c) {
                const uint2 ui = *reinterpret_cast<const uint2*>(ei + c * 16);
                const uint2 uj = *reinterpret_cast<const uint2*>(ej + c * 16);
                U32F a0, a1, b0, b1;
                a0.u = ui.x; a1.u = ui.y;
                b0.u = uj.x; b1.u = uj.y;
                const uint2 ui2 = *reinterpret_cast<const uint2*>(ei + c * 16 + 4);
                const uint2 uj2 = *reinterpret_cast<const uint2*>(ej + c * 16 + 4);
                U32F a2, a3, b2, b3;
                a2.u = ui2.x; a3.u = ui2.y;
                b2.u = uj2.x; b3.u = uj2.y;
                f16x2 x0 = a0.h * b0.h;   // v_pk_mul_f16
                f16x2 x1 = a1.h * b1.h;
                f16x2 x2 = a2.h * b2.h;
                f16x2 x3 = a3.h * b3.h;
                t_half = dot2acc(x0, w2[c * 4 + 0], t_half);
                t_half = dot2acc(x1, w2[c * 4 + 1], t_half);
                t_half = dot2acc(x2, w2[c * 4 + 2], t_half);
                t_half = dot2acc(x3, w2[c * 4 + 3], t_half);
                F16x8U af;
                af.h2[0] = x0; af.h2[1] = x1; af.h2[2] = x2; af.h2[3] = x3;
                afrag[c] = af.v;
            }
            acc = __builtin_amdgcn_mfma_f32_32x32x16_f16(afrag[0], bfrag[0], acc, 0, 0, 0);
            acc = __builtin_amdgcn_mfma_f32_32x32x16_f16(afrag[1], bfrag[1], acc, 0, 0, 0);
            acc = __builtin_amdgcn_mfma_f32_32x32x16_f16(afrag[2], bfrag[2], acc, 0, 0, 0);
            acc = __builtin_amdgcn_mfma_f32_32x32x16_f16(afrag[3], bfrag[3], acc, 0, 0, 0);

            const float t_full = t_half + __shfl_xor(t_half, 32, 64);

            // epilogue: s[row] = sum_a relu(acc + attb[a]) * p[a], halving butterfly
            float V[16];
            #pragma unroll
            for (int k = 0; k < 16; ++k)
                V[k] = fmaxf(acc[k] + attb_l, 0.f) * p_l;
            {   // m=1: 16 -> 8 (bit set keeps HIGH labels)
                const bool up = (lane & 1);
                #pragma unroll
                for (int k = 0; k < 8; ++k) {
                    float snd = up ? V[k] : V[k + 8];
                    float kp  = up ? V[k + 8] : V[k];
                    V[k] = kp + __shfl_xor(snd, 1, 64);
                }
            }
            {   // m=2: 8 -> 4
                const bool up = (lane & 2);
                #pragma unroll
                for (int k = 0; k < 4; ++k) {
                    float snd = up ? V[k] : V[k + 4];
                    float kp  = up ? V[k + 4] : V[k];
                    V[k] = kp + __shfl_xor(snd, 2, 64);
                }
            }
            {   // m=4: 4 -> 2
                const bool up = (lane & 4);
                #pragma unroll
                for (int k = 0; k < 2; ++k) {
                    float snd = up ? V[k] : V[k + 2];
                    float kp  = up ? V[k + 2] : V[k];
                    V[k] = kp + __shfl_xor(snd, 4, 64);
                }
            }
            {   // m=8: 2 -> 1
                const bool up = (lane & 8);
                float snd = up ? V[0] : V[1];
                float kp  = up ? V[1] : V[0];
                V[0] = kp + __shfl_xor(snd, 8, 64);
            }
            const float tot = V[0] + __shfl_xor(V[0], 16, 64);

            // final label: reg k* = bit-reversed low-4 lane bits
            const int l4 = lane & 15;
            const int kstar = ((l4 & 1) << 3) | (((l4 >> 1) & 1) << 2) |
                              (((l4 >> 2) & 1) << 1) | ((l4 >> 3) & 1);
            const int row = (kstar & 3) + 8 * (kstar >> 2) + 4 * h;
            const float tmine = __shfl(t_full, row, 64);  // t for pair tile*32+row
            const int pp = tile * 32 + row;
            if (((lane & 16) == 0) && pp < NPAIRS) {
                scv[tt] = tot;
                tv[tt]  = tmine;
            }
        }
    }

    // ---- softmax over all pairs: max, sum e, sum e*t ----
    float lmax = -INFINITY;
    #pragma unroll
    for (int k = 0; k < MAXT; ++k) lmax = fmaxf(lmax, scv[k]);
    #pragma unroll
    for (int m = 1; m < 64; m <<= 1) lmax = fmaxf(lmax, __shfl_xor(lmax, m, 64));
    if (lane == 0) red_max[wid] = lmax;
    __syncthreads();
    const float gmax = fmaxf(fmaxf(red_max[0], red_max[1]),
                             fmaxf(red_max[2], red_max[3]));

    float lsum = 0.f, lsumt = 0.f;
    #pragma unroll
    for (int k = 0; k < MAXT; ++k) {
        float e = __expf(scv[k] - gmax);   // exp(-inf) = 0 for masked slots
        lsum  += e;
        lsumt += e * tv[k];
    }
    #pragma unroll
    for (int m = 1; m < 64; m <<= 1) {
        lsum  += __shfl_xor(lsum, m, 64);
        lsumt += __shfl_xor(lsumt, m, 64);
    }
    if (lane == 0) { red_sum[wid] = lsum; red_sumt[wid] = lsumt; }
    __syncthreads();

    if (tid == 0) {
        float S  = red_sum[0] + red_sum[1] + red_sum[2] + red_sum[3];
        float ST = red_sumt[0] + red_sumt[1] + red_sumt[2] + red_sumt[3];
        float csum = 0.f;
        for (int i = 0; i < NFIELDS; ++i) csum += coeff_s[i];
        out[b] = ST / S + csum + bias[0];
    }
}

extern "C" void kernel_launch(void* const* d_in, const int* in_sizes, int n_in,
                              void* d_out, int out_size, void* d_ws, size_t ws_size,
                              hipStream_t stream) {
    const int*   features    = (const int*)d_in[0];
    const float* emb_table   = (const float*)d_in[1];
    const float* coeff_table = (const float*)d_in[2];
    const float* bias        = (const float*)d_in[3];
    const float* att_w       = (const float*)d_in[4];
    const float* att_b       = (const float*)d_in[5];
    const float* pvec        = (const float*)d_in[6];
    const float* wvec        = (const float*)d_in[7];
    float* out = (float*)d_out;

    const int batch = in_sizes[0] / NFIELDS;   // 2048
    afm_kernel<<<batch, NTHREADS, 0, stream>>>(
        features, emb_table, coeff_table, bias, att_w, att_b, pvec, wvec, out);
}

// Round 3
// 36.283 us; speedup vs baseline: 6.6638x; 1.2454x over previous
//
#include <hip/hip_runtime.h>
#include <hip/hip_fp16.h>
#include <math.h>

#define NFIELDS 50
#define EMBD 64
#define ATTD 32
#define NPAIRS 1225
#define NPAD 1248          // 39 * 32
#define NTILES 39
#define NTHREADS 256
#define NWAVES 4
#define MAXT 10
#define NFPAD 51           // chunk-row padding (fields)

typedef _Float16 f16x8 __attribute__((ext_vector_type(8)));
typedef _Float16 f16x2 __attribute__((ext_vector_type(2)));
typedef float f32x16 __attribute__((ext_vector_type(16)));

union F16x8U { f16x8 v; f16x2 h2[4]; unsigned int u[4]; uint4 q; };
union U32F { unsigned int u; f16x2 h; };

__device__ __forceinline__ float dot2acc(f16x2 a, f16x2 b, float c) {
#if __has_builtin(__builtin_amdgcn_fdot2)
    return __builtin_amdgcn_fdot2(a, b, c, false);
#else
    return c + (float)a[0] * (float)b[0] + (float)a[1] * (float)b[1];
#endif
}

__launch_bounds__(NTHREADS, 3)
__global__ void afm_kernel(const int* __restrict__ features,
                           const float* __restrict__ emb_table,
                           const float* __restrict__ coeff_table,
                           const float* __restrict__ bias,
                           const float* __restrict__ att_w,
                           const float* __restrict__ att_b,
                           const float* __restrict__ pvec,
                           const float* __restrict__ wvec,
                           float* __restrict__ out)
{
    // chunk-major: chunk q = h*4 + c holds logical dims d = c*16 + h*8 + [0..8)
    // cross-lane field stride = 16B  ->  measured-optimal ds_read_b128 pattern
    __shared__ __align__(16) unsigned short emb3[8][NFPAD][8];
    __shared__ unsigned short pair_s[NPAD];    // (i<<8)|j
    __shared__ int   feat_s[NFIELDS];
    __shared__ float coeff_s[NFIELDS];
    __shared__ float red_max[NWAVES], red_sum[NWAVES], red_sumt[NWAVES];

    const int b    = blockIdx.x;
    const int tid  = threadIdx.x;
    const int lane = tid & 63;
    const int wid  = tid >> 6;
    const int col  = lane & 31;   // MFMA output col = PAIR within tile
    const int h    = lane >> 5;   // k-group half
    const int h4   = h * 4;

    // ---- phase 0a: features, coeff, packed pair table ----
    if (tid < NFIELDS) {
        int f = features[b * NFIELDS + tid];
        feat_s[tid] = f;
        coeff_s[tid] = coeff_table[f];
    }
    if (tid >= 64 && tid < 64 + NFIELDS - 1) {
        int i = tid - 64;                         // row 0..48
        int off = i * NFIELDS - (i * (i + 1)) / 2;
        int cnt = NFIELDS - 1 - i;
        for (int k = 0; k < cnt; ++k)
            pair_s[off + k] = (unsigned short)((i << 8) | (i + 1 + k));
    }
    if (tid == 113) {
        for (int q = NPAIRS; q < NPAD; ++q) pair_s[q] = (unsigned short)1; // (0,1)
    }

    // ---- per-lane register weights (A-operand = att_w, stationary) ----
    // afragW[c][e] = W[row=col][c*16 + h*8 + e]
    f16x8 afragW[4];
    f16x2 w2[16];
    #pragma unroll
    for (int c = 0; c < 4; ++c) {
        const int d0 = c * 16 + h * 8;
        const float4 wa0 = *reinterpret_cast<const float4*>(&att_w[col * EMBD + d0]);
        const float4 wa1 = *reinterpret_cast<const float4*>(&att_w[col * EMBD + d0 + 4]);
        F16x8U bf;
        bf.v[0] = (_Float16)wa0.x; bf.v[1] = (_Float16)wa0.y;
        bf.v[2] = (_Float16)wa0.z; bf.v[3] = (_Float16)wa0.w;
        bf.v[4] = (_Float16)wa1.x; bf.v[5] = (_Float16)wa1.y;
        bf.v[6] = (_Float16)wa1.z; bf.v[7] = (_Float16)wa1.w;
        afragW[c] = bf.v;
        const float4 wv0 = *reinterpret_cast<const float4*>(&wvec[d0]);
        const float4 wv1 = *reinterpret_cast<const float4*>(&wvec[d0 + 4]);
        f16x2 t0; t0[0] = (_Float16)wv0.x; t0[1] = (_Float16)wv0.y; w2[c * 4 + 0] = t0;
        f16x2 t1; t1[0] = (_Float16)wv0.z; t1[1] = (_Float16)wv0.w; w2[c * 4 + 1] = t1;
        f16x2 t2; t2[0] = (_Float16)wv1.x; t2[1] = (_Float16)wv1.y; w2[c * 4 + 2] = t2;
        f16x2 t3; t3[0] = (_Float16)wv1.z; t3[1] = (_Float16)wv1.w; w2[c * 4 + 3] = t3;
    }
    // per-reg output-row constants: row = (reg&3) + 8*(reg>>2) + 4*h
    float attb_r[16], p_r[16];
    #pragma unroll
    for (int reg = 0; reg < 16; ++reg) {
        const int r = (reg & 3) + 8 * (reg >> 2) + 4 * h;
        attb_r[reg] = att_b[r];
        p_r[reg]    = pvec[r];
    }
    __syncthreads();

    // ---- phase 0b: gather embeddings -> f16 chunk-major LDS ----
    for (int idx = tid; idx < NFIELDS * 16; idx += NTHREADS) {
        const int f  = idx >> 4;
        const int d0 = (idx & 15) * 4;            // logical dim start
        const float4 v = *reinterpret_cast<const float4*>(
            &emb_table[(size_t)feat_s[f] * EMBD + d0]);
        const int c  = d0 >> 4;
        const int hh = (d0 >> 3) & 1;
        const int e0 = d0 & 7;                    // 0 or 4
        U32F t0, t1;
        t0.h[0] = (_Float16)v.x; t0.h[1] = (_Float16)v.y;
        t1.h[0] = (_Float16)v.z; t1.h[1] = (_Float16)v.w;
        uint2 pk; pk.x = t0.u; pk.y = t1.u;
        *reinterpret_cast<uint2*>(&emb3[hh * 4 + c][f][e0]) = pk;
    }
    __syncthreads();

    // ---- main: per-wave 32-pair MFMA tiles (cols = pairs, rows = att units) ----
    float scv[MAXT], tv[MAXT];
    #pragma unroll
    for (int k = 0; k < MAXT; ++k) { scv[k] = -INFINITY; tv[k] = 0.f; }

    #pragma unroll
    for (int tt = 0; tt < MAXT; ++tt) {
        const int tile = wid + tt * NWAVES;
        if (tile < NTILES) {
            const int pidx = tile * 32 + col;
            const unsigned int ij = pair_s[pidx];
            const int fi = ij >> 8;
            const int fj = ij & 255;

            f32x16 acc;
            #pragma unroll
            for (int k = 0; k < 16; ++k) acc[k] = 0.f;

            float t_half = 0.f;
            #pragma unroll
            for (int c = 0; c < 4; ++c) {
                F16x8U ai, aj;
                ai.q = *reinterpret_cast<const uint4*>(&emb3[h4 + c][fi][0]);
                aj.q = *reinterpret_cast<const uint4*>(&emb3[h4 + c][fj][0]);
                const f16x2 x0 = ai.h2[0] * aj.h2[0];   // v_pk_mul_f16
                const f16x2 x1 = ai.h2[1] * aj.h2[1];
                const f16x2 x2 = ai.h2[2] * aj.h2[2];
                const f16x2 x3 = ai.h2[3] * aj.h2[3];
                t_half = dot2acc(x0, w2[c * 4 + 0], t_half);
                t_half = dot2acc(x1, w2[c * 4 + 1], t_half);
                t_half = dot2acc(x2, w2[c * 4 + 2], t_half);
                t_half = dot2acc(x3, w2[c * 4 + 3], t_half);
                F16x8U bf;
                bf.h2[0] = x0; bf.h2[1] = x1; bf.h2[2] = x2; bf.h2[3] = x3;
                acc = __builtin_amdgcn_mfma_f32_32x32x16_f16(afragW[c], bf.v, acc, 0, 0, 0);
            }

            // epilogue: in-register over 16 rows, then one half-swap
            float sp = 0.f;
            #pragma unroll
            for (int reg = 0; reg < 16; ++reg)
                sp = fmaf(fmaxf(acc[reg] + attb_r[reg], 0.f), p_r[reg], sp);
            const float sc = sp + __shfl_xor(sp, 32, 64);
            const float tf = t_half + __shfl_xor(t_half, 32, 64);
            if (h == 0 && pidx < NPAIRS) { scv[tt] = sc; tv[tt] = tf; }
        }
    }

    // ---- softmax over all pairs: max, sum e, sum e*t ----
    float lmax = -INFINITY;
    #pragma unroll
    for (int k = 0; k < MAXT; ++k) lmax = fmaxf(lmax, scv[k]);
    #pragma unroll
    for (int m = 1; m < 64; m <<= 1) lmax = fmaxf(lmax, __shfl_xor(lmax, m, 64));
    if (lane == 0) red_max[wid] = lmax;
    __syncthreads();
    const float gmax = fmaxf(fmaxf(red_max[0], red_max[1]),
                             fmaxf(red_max[2], red_max[3]));

    float lsum = 0.f, lsumt = 0.f;
    #pragma unroll
    for (int k = 0; k < MAXT; ++k) {
        float e = __expf(scv[k] - gmax);   // exp(-inf) = 0 for masked slots
        lsum  += e;
        lsumt += e * tv[k];
    }
    #pragma unroll
    for (int m = 1; m < 64; m <<= 1) {
        lsum  += __shfl_xor(lsum, m, 64);
        lsumt += __shfl_xor(lsumt, m, 64);
    }
    if (lane == 0) { red_sum[wid] = lsum; red_sumt[wid] = lsumt; }
    __syncthreads();

    if (tid == 0) {
        float S  = red_sum[0] + red_sum[1] + red_sum[2] + red_sum[3];
        float ST = red_sumt[0] + red_sumt[1] + red_sumt[2] + red_sumt[3];
        float csum = 0.f;
        for (int i = 0; i < NFIELDS; ++i) csum += coeff_s[i];
        out[b] = ST / S + csum + bias[0];
    }
}

extern "C" void kernel_launch(void* const* d_in, const int* in_sizes, int n_in,
                              void* d_out, int out_size, void* d_ws, size_t ws_size,
                              hipStream_t stream) {
    const int*   features    = (const int*)d_in[0];
    const float* emb_table   = (const float*)d_in[1];
    const float* coeff_table = (const float*)d_in[2];
    const float* bias        = (const float*)d_in[3];
    const float* att_w       = (const float*)d_in[4];
    const float* att_b       = (const float*)d_in[5];
    const float* pvec        = (const float*)d_in[6];
    const float* wvec        = (const float*)d_in[7];
    float* out = (float*)d_out;

    const int batch = in_sizes[0] / NFIELDS;   // 2048
    afm_kernel<<<batch, NTHREADS, 0, stream>>>(
        features, emb_table, coeff_table, bias, att_w, att_b, pvec, wvec, out);
}

// Round 4
// 35.937 us; speedup vs baseline: 6.7280x; 1.0096x over previous
//
#include <hip/hip_runtime.h>
#include <hip/hip_fp16.h>
#include <math.h>

#define NFIELDS 50
#define EMBD 64
#define NPAIRS 1225
#define NTILEPAD 40
#define NPAD (NTILEPAD * 32)      // 1280
#define NTHREADS 256
#define NWAVES 4
#define NITER (NTILEPAD / NWAVES) // 10
#define QPT (NPAD / NTHREADS)     // 5
#define NFPAD 51

typedef _Float16 f16x8 __attribute__((ext_vector_type(8)));
typedef _Float16 f16x2 __attribute__((ext_vector_type(2)));
typedef float f32x16 __attribute__((ext_vector_type(16)));

union F16x8U { f16x8 v; f16x2 h2[4]; unsigned int u[4]; uint4 q; };
union U32F { unsigned int u; f16x2 h; };

__device__ __forceinline__ float dot2acc(f16x2 a, f16x2 b, float c) {
#if __has_builtin(__builtin_amdgcn_fdot2)
    return __builtin_amdgcn_fdot2(a, b, c, false);
#else
    return c + (float)a[0] * (float)b[0] + (float)a[1] * (float)b[1];
#endif
}

#define MNEG (-1e30f)

__launch_bounds__(NTHREADS, 4)
__global__ void afm_kernel(const int* __restrict__ features,
                           const float* __restrict__ emb_table,
                           const float* __restrict__ coeff_table,
                           const float* __restrict__ bias,
                           const float* __restrict__ att_w,
                           const float* __restrict__ att_b,
                           const float* __restrict__ pvec,
                           const float* __restrict__ wvec,
                           float* __restrict__ out)
{
    // chunk-major: chunk q = h*4 + c holds logical dims d = c*16 + h*8 + [0..8)
    __shared__ __align__(16) unsigned short emb3[8][NFPAD][8];
    __shared__ unsigned short pair_s[NPAD];    // (i<<8)|j
    __shared__ int   feat_s[NFIELDS];
    __shared__ float red_m[NWAVES], red_s[NWAVES], red_st[NWAVES];
    __shared__ float red_csum;

    const int b    = blockIdx.x;
    const int tid  = threadIdx.x;
    const int lane = tid & 63;
    const int wid  = tid >> 6;
    const int col  = lane & 31;   // MFMA output col = PAIR within tile
    const int h    = lane >> 5;   // k-group half
    const int h4   = h * 4;

    // ---- phase 0a: features, pair table (closed form), coeff+bias reduce ----
    int myfeat = 0;
    if (tid < NFIELDS) {
        myfeat = features[b * NFIELDS + tid];
        feat_s[tid] = myfeat;
    }

    #pragma unroll
    for (int k = 0; k < QPT; ++k) {
        const int q = tid * QPT + k;
        int i = 0, j = 1;
        if (q < NPAIRS) {
            const float s = sqrtf((float)(9801 - 8 * q));
            i = (int)((99.0f - s) * 0.5f);
            const int off = i * NFIELDS - ((i * (i + 1)) >> 1);
            j = i + 1 + (q - off);
        }
        pair_s[q] = (unsigned short)((i << 8) | j);
    }

    if (wid == 0) {   // coeff sum + bias via wave shuffle reduce
        float cacc = 0.f;
        if (tid < NFIELDS)       cacc = coeff_table[myfeat];
        else if (tid == NFIELDS) cacc = bias[0];
        #pragma unroll
        for (int m = 1; m < 64; m <<= 1) cacc += __shfl_xor(cacc, m, 64);
        if (tid == 0) red_csum = cacc;
    }

    // ---- per-lane register weights (A-operand = att_w, stationary) ----
    f16x8 afragW[4];
    f16x2 w2[16];
    #pragma unroll
    for (int c = 0; c < 4; ++c) {
        const int d0 = c * 16 + h * 8;
        const float4 wa0 = *reinterpret_cast<const float4*>(&att_w[col * EMBD + d0]);
        const float4 wa1 = *reinterpret_cast<const float4*>(&att_w[col * EMBD + d0 + 4]);
        F16x8U bf;
        bf.v[0] = (_Float16)wa0.x; bf.v[1] = (_Float16)wa0.y;
        bf.v[2] = (_Float16)wa0.z; bf.v[3] = (_Float16)wa0.w;
        bf.v[4] = (_Float16)wa1.x; bf.v[5] = (_Float16)wa1.y;
        bf.v[6] = (_Float16)wa1.z; bf.v[7] = (_Float16)wa1.w;
        afragW[c] = bf.v;
        const float4 wv0 = *reinterpret_cast<const float4*>(&wvec[d0]);
        const float4 wv1 = *reinterpret_cast<const float4*>(&wvec[d0 + 4]);
        f16x2 t0; t0[0] = (_Float16)wv0.x; t0[1] = (_Float16)wv0.y; w2[c * 4 + 0] = t0;
        f16x2 t1; t1[0] = (_Float16)wv0.z; t1[1] = (_Float16)wv0.w; w2[c * 4 + 1] = t1;
        f16x2 t2; t2[0] = (_Float16)wv1.x; t2[1] = (_Float16)wv1.y; w2[c * 4 + 2] = t2;
        f16x2 t3; t3[0] = (_Float16)wv1.z; t3[1] = (_Float16)wv1.w; w2[c * 4 + 3] = t3;
    }
    // per-reg output-row constants: row = (reg&3) + 8*(reg>>2) + 4*h
    float attb_r[16], p_r[16];
    #pragma unroll
    for (int reg = 0; reg < 16; ++reg) {
        const int r = (reg & 3) + 8 * (reg >> 2) + 4 * h;
        attb_r[reg] = att_b[r];
        p_r[reg]    = pvec[r];
    }
    __syncthreads();

    // ---- phase 0b: gather embeddings -> f16 chunk-major LDS ----
    for (int idx = tid; idx < NFIELDS * 16; idx += NTHREADS) {
        const int f  = idx >> 4;
        const int d0 = (idx & 15) * 4;            // logical dim start
        const float4 v = *reinterpret_cast<const float4*>(
            &emb_table[(size_t)feat_s[f] * EMBD + d0]);
        const int c  = d0 >> 4;
        const int hh = (d0 >> 3) & 1;
        const int e0 = d0 & 7;                    // 0 or 4
        U32F t0, t1;
        t0.h[0] = (_Float16)v.x; t0.h[1] = (_Float16)v.y;
        t1.h[0] = (_Float16)v.z; t1.h[1] = (_Float16)v.w;
        uint2 pk; pk.x = t0.u; pk.y = t1.u;
        *reinterpret_cast<uint2*>(&emb3[hh * 4 + c][f][e0]) = pk;
    }
    __syncthreads();

    // ---- main: branch-free padded tiles, online softmax state per lane ----
    float m_run = MNEG, s_run = 0.f, st_run = 0.f;

    #pragma unroll 2
    for (int tt = 0; tt < NITER; ++tt) {
        const int tile = wid + tt * NWAVES;
        const int pidx = tile * 32 + col;
        const unsigned int ij = pair_s[pidx];
        const int fi = ij >> 8;
        const int fj = ij & 255;

        f32x16 acc;
        #pragma unroll
        for (int reg = 0; reg < 16; ++reg) acc[reg] = attb_r[reg];   // bias in acc-init

        float t_half = 0.f;
        #pragma unroll
        for (int c = 0; c < 4; ++c) {
            F16x8U ai, aj;
            ai.q = *reinterpret_cast<const uint4*>(&emb3[h4 + c][fi][0]);
            aj.q = *reinterpret_cast<const uint4*>(&emb3[h4 + c][fj][0]);
            const f16x2 x0 = ai.h2[0] * aj.h2[0];   // v_pk_mul_f16
            const f16x2 x1 = ai.h2[1] * aj.h2[1];
            const f16x2 x2 = ai.h2[2] * aj.h2[2];
            const f16x2 x3 = ai.h2[3] * aj.h2[3];
            t_half = dot2acc(x0, w2[c * 4 + 0], t_half);
            t_half = dot2acc(x1, w2[c * 4 + 1], t_half);
            t_half = dot2acc(x2, w2[c * 4 + 2], t_half);
            t_half = dot2acc(x3, w2[c * 4 + 3], t_half);
            F16x8U bf;
            bf.h2[0] = x0; bf.h2[1] = x1; bf.h2[2] = x2; bf.h2[3] = x3;
            acc = __builtin_amdgcn_mfma_f32_32x32x16_f16(afragW[c], bf.v, acc, 0, 0, 0);
        }

        // epilogue: relu·p over 16 in-register rows, then one half-swap
        float sp = 0.f;
        #pragma unroll
        for (int reg = 0; reg < 16; ++reg)
            sp = fmaf(fmaxf(acc[reg], 0.f), p_r[reg], sp);
        const float sc = sp + __shfl_xor(sp, 32, 64);
        const float tf = t_half + __shfl_xor(t_half, 32, 64);

        // online update (h=0/h=1 duplicates cancel in ST/S)
        const bool valid = (pidx < NPAIRS);
        const float scm = valid ? sc : MNEG;
        const float mn  = fmaxf(m_run, scm);
        const float scale = __expf(m_run - mn);
        const float e     = valid ? __expf(sc - mn) : 0.f;
        s_run  = s_run  * scale + e;
        st_run = st_run * scale + e * tf;
        m_run  = mn;
    }

    // ---- merge online states: 64-lane butterfly, then cross-wave via LDS ----
    #pragma unroll
    for (int m = 1; m < 64; m <<= 1) {
        const float m2  = __shfl_xor(m_run, m, 64);
        const float s2  = __shfl_xor(s_run, m, 64);
        const float st2 = __shfl_xor(st_run, m, 64);
        const float mn  = fmaxf(m_run, m2);
        const float ea  = __expf(m_run - mn);
        const float eb  = __expf(m2 - mn);
        s_run  = s_run * ea + s2 * eb;
        st_run = st_run * ea + st2 * eb;
        m_run  = mn;
    }
    if (lane == 0) { red_m[wid] = m_run; red_s[wid] = s_run; red_st[wid] = st_run; }
    __syncthreads();

    if (tid == 0) {
        float M = red_m[0], S = red_s[0], ST = red_st[0];
        #pragma unroll
        for (int wq = 1; wq < NWAVES; ++wq) {
            const float mn = fmaxf(M, red_m[wq]);
            const float ea = __expf(M - mn);
            const float eb = __expf(red_m[wq] - mn);
            S  = S * ea + red_s[wq] * eb;
            ST = ST * ea + red_st[wq] * eb;
            M  = mn;
        }
        out[b] = ST / S + red_csum;
    }
}

extern "C" void kernel_launch(void* const* d_in, const int* in_sizes, int n_in,
                              void* d_out, int out_size, void* d_ws, size_t ws_size,
                              hipStream_t stream) {
    const int*   features    = (const int*)d_in[0];
    const float* emb_table   = (const float*)d_in[1];
    const float* coeff_table = (const float*)d_in[2];
    const float* bias        = (const float*)d_in[3];
    const float* att_w       = (const float*)d_in[4];
    const float* att_b       = (const float*)d_in[5];
    const float* pvec        = (const float*)d_in[6];
    const float* wvec        = (const float*)d_in[7];
    float* out = (float*)d_out;

    const int batch = in_sizes[0] / NFIELDS;   // 2048
    afm_kernel<<<batch, NTHREADS, 0, stream>>>(
        features, emb_table, coeff_table, bias, att_w, att_b, pvec, wvec, out);
}